// Round 3
// baseline (419.746 us; speedup 1.0000x reference)
//
#include <hip/hip_runtime.h>
#include <hip/hip_bf16.h>
#include <stdint.h>

// Problem: B=8, S=2048, F=1024 single-head causal self-attention.
// R4: softmax folded into scores epilogue via fixed-offset exp (P'=exp(s-16)).
// R5: k_qkv on 256x256 8-phase schedule (T2 swizzle: bank conflicts 1.26e7->0).
// R6: asm ds_read + post-barrier lgkmcnt -> no change (147us). Diagnosis: 700 TF
//     == m218's "8-phase with drain0" signature (682 TF).
// R7: root cause: every barrier/waitcnt asm had a "memory" clobber -> SIInsertWaitcnts
//     conservatively emits s_waitcnt vmcnt(0) lgkmcnt(0) BEFORE each such asm, so the
//     12-deep gload pipeline drains every phase and the hand-written vmcnt(8) is dead.
//     Fix: __builtin_amdgcn_s_barrier() (no auto-wait) + clobber-free waitcnt asm +
//     sched_barrier(0) pins (rule #18 / m201 template, followed EXACTLY this time).
//     Also: ds_read bases hoisted to one VGPR, per-read address via offset: immediates.

#define S_LEN 2048
#define F_DIM 1024
#define NBATCH 8
#define BS_TOT (NBATCH * S_LEN)   // 16384 rows

typedef __attribute__((ext_vector_type(8))) short bf16x8;
typedef __attribute__((ext_vector_type(4))) float f32x4;
typedef unsigned short u16;

__device__ __forceinline__ u16 f32_to_bf16_rne(float f) {
    union { float f; uint32_t u; } v; v.f = f;
    uint32_t u = v.u;
    u += 0x7FFFu + ((u >> 16) & 1u);
    return (u16)(u >> 16);
}
__device__ __forceinline__ float bf16_to_f32(u16 h) {
    union { uint32_t u; float f; } v; v.u = ((uint32_t)h) << 16;
    return v.f;
}

// async global->LDS, 16B per lane per instruction (global_load_lds_dwordx4)
__device__ __forceinline__ void gload_lds16(const u16* g, u16* l) {
    __builtin_amdgcn_global_load_lds(
        (const __attribute__((address_space(1))) void*)g,
        (__attribute__((address_space(3))) void*)l,
        16, 0, 0);
}

typedef const __attribute__((address_space(3))) u16* lds_cptr;
// ds_read_b128 from base VGPR + literal byte offset. NO clobbers: the pending load
// must stay invisible to SIInsertWaitcnts (a "memory" clobber forces a full
// vmcnt(0)+lgkmcnt(0) drain before the asm -- the R5/R6 30%-MfmaUtil bug).
#define DSR(dst, base, OFF) \
    asm volatile("ds_read_b128 %0, %1 offset:" #OFF \
                 : "=v"(dst) : "v"((lds_cptr)(base)))

// ---------------- fp32 -> bf16 converts ----------------
__global__ __launch_bounds__(256) void cvt_f32_bf16(const float* __restrict__ in,
                                                    u16* __restrict__ out, int n) {
    int i = (blockIdx.x * 256 + threadIdx.x) * 4;
    if (i + 3 < n) {
        float4 f = *(const float4*)(in + i);
        ushort4 o;
        o.x = f32_to_bf16_rne(f.x); o.y = f32_to_bf16_rne(f.y);
        o.z = f32_to_bf16_rne(f.z); o.w = f32_to_bf16_rne(f.w);
        *(ushort4*)(out + i) = o;
    }
}

__global__ __launch_bounds__(256) void cvt_w3(const float* __restrict__ Wq,
                                              const float* __restrict__ Wk,
                                              const float* __restrict__ Wv,
                                              u16* __restrict__ Wb) {
    const int which = blockIdx.y;
    const float* in = (which == 0) ? Wq : (which == 1) ? Wk : Wv;
    int i = (blockIdx.x * 256 + threadIdx.x) * 4;
    float4 f = *(const float4*)(in + i);
    ushort4 o;
    o.x = f32_to_bf16_rne(f.x); o.y = f32_to_bf16_rne(f.y);
    o.z = f32_to_bf16_rne(f.z); o.w = f32_to_bf16_rne(f.w);
    *(ushort4*)(Wb + (size_t)which * F_DIM * F_DIM + i) = o;
}

// ---------------- core 128x128 B^T GEMM tile (m97 structure) ----------------
// Used by k_scores / k_pv.
template<class Epi>
__device__ __forceinline__ void gemm_tile_128(
    const u16* __restrict__ A, int lda,
    const u16* __restrict__ Bt, int ldb,
    int m0, int n0, int K, float alpha, Epi epi)
{
    __shared__ u16 la[128 * 32];
    __shared__ u16 lb[128 * 32];

    const int tid  = threadIdx.x;
    const int lane = tid & 63;
    const int wave = tid >> 6;
    const int wm = (wave & 1) * 64;
    const int wn = (wave >> 1) * 64;

    f32x4 acc[4][4];
#pragma unroll
    for (int mt = 0; mt < 4; mt++)
#pragma unroll
        for (int nt = 0; nt < 4; nt++)
            acc[mt][nt] = f32x4{0.f, 0.f, 0.f, 0.f};

    const int mrow = wm + (lane & 15);
    const int nrow = wn + (lane & 15);
    const int koff = (lane >> 4) * 8;

    const int cb0 = wave * 64;
    const int cb1 = wave * 64 + 256;
    const int lrow = lane >> 2;
    const int lcol = (lane & 3) * 8;
    const u16* pa0 = A  + (size_t)(m0 + (cb0 >> 2) + lrow) * lda + lcol;
    const u16* pa1 = A  + (size_t)(m0 + (cb1 >> 2) + lrow) * lda + lcol;
    const u16* pb0 = Bt + (size_t)(n0 + (cb0 >> 2) + lrow) * ldb + lcol;
    const u16* pb1 = Bt + (size_t)(n0 + (cb1 >> 2) + lrow) * ldb + lcol;
    u16* qa0 = la + cb0 * 8;
    u16* qa1 = la + cb1 * 8;
    u16* qb0 = lb + cb0 * 8;
    u16* qb1 = lb + cb1 * 8;

    for (int kk = 0; kk < K; kk += 32) {
        __syncthreads();
        gload_lds16(pa0 + kk, qa0);
        gload_lds16(pa1 + kk, qa1);
        gload_lds16(pb0 + kk, qb0);
        gload_lds16(pb1 + kk, qb1);
        __syncthreads();

        bf16x8 fa[4], fb[4];
#pragma unroll
        for (int t = 0; t < 4; t++) {
            fa[t] = *(const bf16x8*)(la + (mrow + t * 16) * 32 + koff);
            fb[t] = *(const bf16x8*)(lb + (nrow + t * 16) * 32 + koff);
        }
#pragma unroll
        for (int mt = 0; mt < 4; mt++)
#pragma unroll
            for (int nt = 0; nt < 4; nt++)
                acc[mt][nt] = __builtin_amdgcn_mfma_f32_16x16x32_bf16(
                    fa[mt], fb[nt], acc[mt][nt], 0, 0, 0);
    }

    // C/D layout col=lane&15, row=(lane>>4)*4+reg  [verified m89/m91]
    const int col   = lane & 15;
    const int rquad = (lane >> 4) * 4;
#pragma unroll
    for (int mt = 0; mt < 4; mt++)
#pragma unroll
        for (int nt = 0; nt < 4; nt++) {
            const int n = n0 + wn + nt * 16 + col;
#pragma unroll
            for (int r = 0; r < 4; r++) {
                const int m = m0 + wm + mt * 16 + rquad + r;
                epi(m, n, acc[mt][nt][r] * alpha);
            }
        }
}

// ---------------- 256x256 8-phase B^T GEMM tile (m201 structure) ----------------
// 512 threads = 8 waves 2(M)x4(N); per-wave 128x64 via 8x4 mfma_f32_16x16x32_bf16.
// LDS [2 buf][A,B][2 kk-plane][256*32 u16] = 128 KiB. T2 granule-XOR swizzle
// (g ^ ((row>>1)&3)), linear gload dest + pre-swizzled global source (rule #21).
// T3/T4: 2 gloads staged/phase, 12 outstanding steady, vmcnt(8) at P2/P4 only
// (drain vmcnt(0) on last 2 tiles). T5 setprio around MFMA clusters.
// Barriers are RAW __builtin_amdgcn_s_barrier(); waitcnts are clobber-free asm;
// sched_barrier(0) pins phase boundaries. WAR safety: each buffer overwrite is
// issued after the barrier that retires its last reader (verified per-slot).
template<class Epi>
__device__ __forceinline__ void gemm_tile_256(
    const u16* __restrict__ A, int lda,
    const u16* __restrict__ Bt, int ldb,
    int m0, int n0, int K, float alpha, Epi epi)
{
    __shared__ u16 lds[2][2][2][8192];   // [buf][A=0/B=1][kk-plane][256*32]

    const int tid  = threadIdx.x;
    const int lane = tid & 63;
    const int wave = tid >> 6;
    const int wm   = (wave >> 2) * 128;
    const int wn   = (wave & 3) * 64;
    const int frow = lane & 15;
    const int g    = lane >> 4;
    const int wvo  = wave * 512;         // u16: wave-uniform gload base within a slot

    f32x4 acc[8][4];
#pragma unroll
    for (int i = 0; i < 8; i++)
#pragma unroll
        for (int j = 0; j < 4; j++) acc[i][j] = f32x4{0.f, 0.f, 0.f, 0.f};

    // ds_read bases: one pointer per (buf, A/B). Row = w*+frow; swizzle nibble
    // (g ^ ((row>>1)&3)) depends only on frow bits 1:2 (w*, mt*16 are 0 mod 16).
    // All mt/nt/plane/half deltas are literal offset: immediates (max 23552 < 64K).
    const int swz = (g ^ ((frow >> 1) & 3)) << 3;          // u16 elements
    const u16* bA0 = &lds[0][0][0][0] + (wm + frow) * 32 + swz;
    const u16* bB0 = &lds[0][1][0][0] + (wn + frow) * 32 + swz;
    const u16* bA1 = bA0 + 32768;                          // buf stride 64 KiB
    const u16* bB1 = bB0 + 32768;

    // Staging: LDS byte off = tid*16 -> row = tid/4, linear granule gL = tid&3.
    // Pre-swizzled global granule gG = gL ^ ((row>>1)&3) = (tid&3)^((tid>>3)&3).
    const int gG = (tid & 3) ^ ((tid >> 3) & 3);
    const u16* pa0 = A  + (size_t)(m0 + (tid >> 2)) * lda + gG * 8;
    const u16* pa1 = pa0 + (size_t)128 * lda;
    const u16* pb0 = Bt + (size_t)(n0 + (tid >> 2)) * ldb + gG * 8;
    const u16* pb1 = pb0 + (size_t)128 * ldb;

    auto stageA = [&](int kc, u16* slot) {
        gload_lds16(pa0 + kc, slot + wvo);
        gload_lds16(pa1 + kc, slot + 4096 + wvo);
    };
    auto stageB = [&](int kc, u16* slot) {
        gload_lds16(pb0 + kc, slot + wvo);
        gload_lds16(pb1 + kc, slot + 4096 + wvo);
    };

    const int nk = K >> 6;

    // prologue: A0(0),B0(0),A1(0),B1(0),A0(1),B0(1) -> 12 loads outstanding
    stageA(0,  &lds[0][0][0][0]);
    stageB(0,  &lds[0][1][0][0]);
    stageA(32, &lds[0][0][1][0]);
    stageB(32, &lds[0][1][1][0]);
    stageA(64, &lds[1][0][0][0]);
    stageB(64, &lds[1][1][0][0]);
    __builtin_amdgcn_sched_barrier(0);
    asm volatile("s_waitcnt vmcnt(8)");    // A0(0),B0(0) landed
    __builtin_amdgcn_s_barrier();
    __builtin_amdgcn_sched_barrier(0);

    for (int t = 0; t < nk; ++t) {
        const int buf = t & 1;
        const u16* bA = buf ? bA1 : bA0;
        const u16* bB = buf ? bB1 : bB0;
        u16* nA1 = &lds[buf ^ 1][0][1][0];
        u16* nB1 = &lds[buf ^ 1][1][1][0];
        u16* nA0 = &lds[buf][0][0][0];
        u16* nB0 = &lds[buf][1][0][0];
        const bool ep = (t >= nk - 2);
        const int kc1 = ((t + 1) << 6);
        const int kc2 = ((t + 2) << 6);

        bf16x8 fa[4], fb[4];

        // -------- P1: kk0, mt0-3 --------
        DSR(fa[0], bA, 0);    DSR(fa[1], bA, 1024);
        DSR(fa[2], bA, 2048); DSR(fa[3], bA, 3072);
        DSR(fb[0], bB, 0);    DSR(fb[1], bB, 1024);
        DSR(fb[2], bB, 2048); DSR(fb[3], bB, 3072);
        if (t + 1 < nk) stageA(kc1 + 32, nA1);
        __builtin_amdgcn_sched_barrier(0);
        __builtin_amdgcn_s_barrier();
        asm volatile("s_waitcnt lgkmcnt(0)");
        __builtin_amdgcn_sched_barrier(0);
        __builtin_amdgcn_s_setprio(1);
#pragma unroll
        for (int mt = 0; mt < 4; mt++)
#pragma unroll
            for (int nt = 0; nt < 4; nt++)
                acc[mt][nt] = __builtin_amdgcn_mfma_f32_16x16x32_bf16(
                    fa[mt], fb[nt], acc[mt][nt], 0, 0, 0);
        __builtin_amdgcn_s_setprio(0);
        __builtin_amdgcn_sched_barrier(0);
        __builtin_amdgcn_s_barrier();
        __builtin_amdgcn_sched_barrier(0);

        // -------- P2: kk0, mt4-7 (fb reused) --------
        DSR(fa[0], bA, 4096); DSR(fa[1], bA, 5120);
        DSR(fa[2], bA, 6144); DSR(fa[3], bA, 7168);
        if (t + 1 < nk) stageB(kc1 + 32, nB1);
        __builtin_amdgcn_sched_barrier(0);
        if (ep) asm volatile("s_waitcnt vmcnt(0)");
        else    asm volatile("s_waitcnt vmcnt(8)");   // A1(t),B1(t) landed
        __builtin_amdgcn_s_barrier();
        asm volatile("s_waitcnt lgkmcnt(0)");
        __builtin_amdgcn_sched_barrier(0);
        __builtin_amdgcn_s_setprio(1);
#pragma unroll
        for (int mt = 0; mt < 4; mt++)
#pragma unroll
            for (int nt = 0; nt < 4; nt++)
                acc[4 + mt][nt] = __builtin_amdgcn_mfma_f32_16x16x32_bf16(
                    fa[mt], fb[nt], acc[4 + mt][nt], 0, 0, 0);
        __builtin_amdgcn_s_setprio(0);
        __builtin_amdgcn_sched_barrier(0);
        __builtin_amdgcn_s_barrier();
        __builtin_amdgcn_sched_barrier(0);

        // -------- P3: kk1, mt0-3 --------
        DSR(fa[0], bA, 16384); DSR(fa[1], bA, 17408);
        DSR(fa[2], bA, 18432); DSR(fa[3], bA, 19456);
        DSR(fb[0], bB, 16384); DSR(fb[1], bB, 17408);
        DSR(fb[2], bB, 18432); DSR(fb[3], bB, 19456);
        if (t + 2 < nk) stageA(kc2, nA0);
        __builtin_amdgcn_sched_barrier(0);
        __builtin_amdgcn_s_barrier();
        asm volatile("s_waitcnt lgkmcnt(0)");
        __builtin_amdgcn_sched_barrier(0);
        __builtin_amdgcn_s_setprio(1);
#pragma unroll
        for (int mt = 0; mt < 4; mt++)
#pragma unroll
            for (int nt = 0; nt < 4; nt++)
                acc[mt][nt] = __builtin_amdgcn_mfma_f32_16x16x32_bf16(
                    fa[mt], fb[nt], acc[mt][nt], 0, 0, 0);
        __builtin_amdgcn_s_setprio(0);
        __builtin_amdgcn_sched_barrier(0);
        __builtin_amdgcn_s_barrier();
        __builtin_amdgcn_sched_barrier(0);

        // -------- P4: kk1, mt4-7 (fb reused) --------
        DSR(fa[0], bA, 20480); DSR(fa[1], bA, 21504);
        DSR(fa[2], bA, 22528); DSR(fa[3], bA, 23552);
        if (t + 2 < nk) stageB(kc2, nB0);
        __builtin_amdgcn_sched_barrier(0);
        if (ep) asm volatile("s_waitcnt vmcnt(0)");
        else    asm volatile("s_waitcnt vmcnt(8)");   // A0(t+1),B0(t+1) landed
        __builtin_amdgcn_s_barrier();
        asm volatile("s_waitcnt lgkmcnt(0)");
        __builtin_amdgcn_sched_barrier(0);
        __builtin_amdgcn_s_setprio(1);
#pragma unroll
        for (int mt = 0; mt < 4; mt++)
#pragma unroll
            for (int nt = 0; nt < 4; nt++)
                acc[4 + mt][nt] = __builtin_amdgcn_mfma_f32_16x16x32_bf16(
                    fa[mt], fb[nt], acc[4 + mt][nt], 0, 0, 0);
        __builtin_amdgcn_s_setprio(0);
        __builtin_amdgcn_sched_barrier(0);
        __builtin_amdgcn_s_barrier();
        __builtin_amdgcn_sched_barrier(0);
    }

    // C/D layout col=lane&15, row=(lane>>4)*4+reg  [verified m89/m91]
    const int col   = lane & 15;
    const int rquad = (lane >> 4) * 4;
#pragma unroll
    for (int mt = 0; mt < 8; mt++)
#pragma unroll
        for (int nt = 0; nt < 4; nt++) {
            const int n = n0 + wn + nt * 16 + col;
#pragma unroll
            for (int r = 0; r < 4; r++) {
                const int m = m0 + wm + mt * 16 + rquad + r;
                epi(m, n, acc[mt][nt][r] * alpha);
            }
        }
}

// ---------------- QKV projection (256x256 8-phase) ----------------
// which 0/1 -> q/k row-major; which 2 -> vT[b][f][s] written transposed.
// Grid 256 x 3, 512 threads; 768 blocks = 3 exact rounds of 256 CUs.
__global__ __launch_bounds__(512) void k_qkv(const u16* __restrict__ xb,
                                             const u16* __restrict__ Wb,
                                             const float* __restrict__ bq,
                                             const float* __restrict__ bk,
                                             const float* __restrict__ bv,
                                             u16* __restrict__ q,
                                             u16* __restrict__ k,
                                             u16* __restrict__ vT) {
    const int which = blockIdx.y;
    const int bx = blockIdx.x;
    const int xcd = bx & 7;
    const int idx = bx >> 3;                       // 0..31
    const int m0 = (xcd * 8 + (idx >> 2)) * 256;   // 64 m-tiles
    const int n0 = (idx & 3) * 256;                // 4 n-tiles
    const float* bias = (which == 0) ? bq : (which == 1) ? bk : bv;
    const u16* W = Wb + (size_t)which * F_DIM * F_DIM;
    u16* o = (which == 0) ? q : k;
    gemm_tile_256(xb, F_DIM, W, F_DIM, m0, n0, F_DIM, 1.0f,
        [&](int m, int n, float v) {
            u16 val = f32_to_bf16_rne(v + bias[n]);
            if (which < 2) {
                o[(size_t)m * F_DIM + n] = val;
            } else {
                // vT[b][n][s], b = m>>11, s = m&2047
                vT[((size_t)(m >> 11) * F_DIM + n) * S_LEN + (m & 2047)] = val;
            }
        });
}

// ---------------- scores -> P' = exp(s-16) masked, bf16, triangular tiles ----------
__global__ __launch_bounds__(256) void k_scores(const u16* __restrict__ q,
                                                const u16* __restrict__ k,
                                                const int* __restrict__ pad,
                                                u16* __restrict__ Pp) {
    const int b = blockIdx.x & 7;
    const int t = blockIdx.x >> 3;        // 0..135 triangular index
    int it = 0, base = 0;
    while (base + it + 1 <= t) { base += it + 1; it++; }
    const int jt = t - base;
    const int* padb = pad + b * S_LEN;
    u16* Pb = Pp + (size_t)b * S_LEN * S_LEN;
    gemm_tile_128(q + (size_t)b * S_LEN * F_DIM, F_DIM,
                  k + (size_t)b * S_LEN * F_DIM, F_DIM,
                  it * 128, jt * 128, F_DIM, 0.03125f,
        [&](int m, int n, float v) {
            u16 o = 0;
            if (n <= m && padb[n] != 0)
                o = f32_to_bf16_rne(__expf(v - 16.0f));
            Pb[(size_t)m * S_LEN + n] = o;
        });
}

// ---------------- row sums of P' -> inv_l (one wave per row, bf16x8 reads) --------
__global__ __launch_bounds__(256) void k_rowsum(const u16* __restrict__ Pp,
                                                float* __restrict__ invl) {
    const int wave = threadIdx.x >> 6, lane = threadIdx.x & 63;
    const int r = blockIdx.x * 4 + wave;      // 0..16383
    const int b = r >> 11, i = r & 2047;
    const int jlim = ((i >> 7) + 1) << 7;     // valid row extent (tile-rounded)
    const u16* row = Pp + (size_t)b * S_LEN * S_LEN + (size_t)i * S_LEN;
    float s = 0.f;
    for (int j0 = lane * 8; j0 < jlim; j0 += 512) {
        bf16x8 v = *(const bf16x8*)(row + j0);
#pragma unroll
        for (int e = 0; e < 8; e++) s += bf16_to_f32((u16)v[e]);
    }
    for (int off = 32; off > 0; off >>= 1) s += __shfl_xor(s, off);
    if (lane == 0) invl[r] = 1.0f / s;
}

// ---------------- PV: out = (P' @ V) * inv_l, k-tiles clipped at diagonal ---------
__global__ __launch_bounds__(256) void k_pv(const u16* __restrict__ Pp,
                                            const u16* __restrict__ vT,
                                            const float* __restrict__ invl,
                                            float* __restrict__ out) {
    const int b = blockIdx.x & 7;
    const int rest = blockIdx.x >> 3;
    const int it = rest >> 3;
    const int nt = rest & 7;
    const int Keff = (it + 1) * 128;
    const float* il = invl + b * S_LEN;
    float* ob = out + (size_t)b * S_LEN * F_DIM;
    gemm_tile_128(Pp + (size_t)b * S_LEN * S_LEN, S_LEN,
                  vT + (size_t)b * F_DIM * S_LEN, S_LEN,
                  it * 128, nt * 128, Keff, 1.0f,
        [&](int m, int n, float v) {
            ob[(size_t)m * F_DIM + n] = v * il[m];
        });
}

extern "C" void kernel_launch(void* const* d_in, const int* in_sizes, int n_in,
                              void* d_out, int out_size, void* d_ws, size_t ws_size,
                              hipStream_t stream) {
    const float* x  = (const float*)d_in[0];
    // d_in[1] = attn_mask (causal tril) — structure hard-coded
    const int* pad  = (const int*)d_in[2];
    const float* Wq = (const float*)d_in[3];
    const float* bq = (const float*)d_in[4];
    const float* Wk = (const float*)d_in[5];
    const float* bk = (const float*)d_in[6];
    const float* Wv = (const float*)d_in[7];
    const float* bv = (const float*)d_in[8];
    float* out = (float*)d_out;

    char* ws = (char*)d_ws;
    // layout:
    //   [0,32M)    q    bf16 [8][2048][1024]
    //   [32,64M)   k    bf16 [8][2048][1024]
    //   [64,96M)   vT   bf16 [8][1024][2048]
    //   [96,160M)  P'   bf16 [8][2048][2048]
    //   [160,192M) xb   bf16 [16384][1024]
    //   [192,198M) Wb   bf16 [3][1024][1024]
    //   [200,200M+64K) invl f32 [16384]
    u16* q    = (u16*)(ws);
    u16* k    = (u16*)(ws + 32ull * 1024 * 1024);
    u16* vT   = (u16*)(ws + 64ull * 1024 * 1024);
    u16* Pp   = (u16*)(ws + 96ull * 1024 * 1024);
    u16* xb   = (u16*)(ws + 160ull * 1024 * 1024);
    u16* Wb   = (u16*)(ws + 192ull * 1024 * 1024);
    float* il = (float*)(ws + 200ull * 1024 * 1024);

    const int BSF = BS_TOT * F_DIM;      // 16,777,216
    const int FF = F_DIM * F_DIM;        // 1,048,576

    cvt_f32_bf16<<<BSF / 1024, 256, 0, stream>>>(x, xb, BSF);
    cvt_w3<<<dim3(FF / 1024, 3), 256, 0, stream>>>(Wq, Wk, Wv, Wb);

    k_qkv<<<dim3(256, 3), 512, 0, stream>>>(xb, Wb, bq, bk, bv, q, k, vT);

    k_scores<<<1088, 256, 0, stream>>>(q, k, pad, Pp);

    k_rowsum<<<4096, 256, 0, stream>>>(Pp, il);

    k_pv<<<1024, 256, 0, stream>>>(Pp, vT, il, out);
}

// Round 4
// 407.005 us; speedup vs baseline: 1.0313x; 1.0313x over previous
//
#include <hip/hip_runtime.h>
#include <hip/hip_bf16.h>
#include <stdint.h>

// Problem: B=8, S=2048, F=1024 single-head causal self-attention.
// R4: softmax folded into scores epilogue via fixed-offset exp (P'=exp(s-16)).
// R5-R7: 256x256 8-phase port of k_qkv -- three sync variants all landed at
//   142-148us / MfmaUtil 30% (m218 "drain-every-phase" signature). The gload
//   pipeline is drained by compiler-inserted waits we cannot suppress at HIP
//   level on this toolchain. ABANDONED; k_qkv reverted to the 128^2 m97 path
//   (known 137us).
// R8: (a) k_rowsum fused into k_scores epilogue (shfl_xor col-reduce +
//   atomicAdd to lsum; lsum zeroed via hipMemsetAsync; k_pv computes 1/l at
//   entry). Kills one dispatch + 34MB P' re-read.
//   (b) k_pv heavy/light interleave: block work scales with Keff=(it+1)*128
//   (16:1 spread); it-ascending order clusters heavy blocks on CUs ->
//   makespan imbalance. it = j&1 ? j>>1 : 15-j>>1 pairs heavy with light.

#define S_LEN 2048
#define F_DIM 1024
#define NBATCH 8
#define BS_TOT (NBATCH * S_LEN)   // 16384 rows

typedef __attribute__((ext_vector_type(8))) short bf16x8;
typedef __attribute__((ext_vector_type(4))) float f32x4;
typedef unsigned short u16;

__device__ __forceinline__ u16 f32_to_bf16_rne(float f) {
    union { float f; uint32_t u; } v; v.f = f;
    uint32_t u = v.u;
    u += 0x7FFFu + ((u >> 16) & 1u);
    return (u16)(u >> 16);
}
__device__ __forceinline__ float bf16_to_f32(u16 h) {
    union { uint32_t u; float f; } v; v.u = ((uint32_t)h) << 16;
    return v.f;
}

// async global->LDS, 16B per lane per instruction (global_load_lds_dwordx4)
__device__ __forceinline__ void gload_lds16(const u16* g, u16* l) {
    __builtin_amdgcn_global_load_lds(
        (const __attribute__((address_space(1))) void*)g,
        (__attribute__((address_space(3))) void*)l,
        16, 0, 0);
}

// ---------------- fp32 -> bf16 converts ----------------
__global__ __launch_bounds__(256) void cvt_f32_bf16(const float* __restrict__ in,
                                                    u16* __restrict__ out, int n) {
    int i = (blockIdx.x * 256 + threadIdx.x) * 4;
    if (i + 3 < n) {
        float4 f = *(const float4*)(in + i);
        ushort4 o;
        o.x = f32_to_bf16_rne(f.x); o.y = f32_to_bf16_rne(f.y);
        o.z = f32_to_bf16_rne(f.z); o.w = f32_to_bf16_rne(f.w);
        *(ushort4*)(out + i) = o;
    }
}

__global__ __launch_bounds__(256) void cvt_w3(const float* __restrict__ Wq,
                                              const float* __restrict__ Wk,
                                              const float* __restrict__ Wv,
                                              u16* __restrict__ Wb) {
    const int which = blockIdx.y;
    const float* in = (which == 0) ? Wq : (which == 1) ? Wk : Wv;
    int i = (blockIdx.x * 256 + threadIdx.x) * 4;
    float4 f = *(const float4*)(in + i);
    ushort4 o;
    o.x = f32_to_bf16_rne(f.x); o.y = f32_to_bf16_rne(f.y);
    o.z = f32_to_bf16_rne(f.z); o.w = f32_to_bf16_rne(f.w);
    *(ushort4*)(Wb + (size_t)which * F_DIM * F_DIM + i) = o;
}

// ---------------- core 128x128 B^T GEMM tile (m97 structure) ----------------
// acc = alpha * sum_k A[m][k]*Bt[n][k]; epilogue via inlined functor epi(m,n,val).
// 256 threads = 4 waves in 2x2, each wave 64x64 via 4x4 mfma_f32_16x16x32_bf16.
// Staging: global_load_lds width=16 (wave-uniform LDS base + lane*16B). [m97]
template<class Epi>
__device__ __forceinline__ void gemm_tile_128(
    const u16* __restrict__ A, int lda,
    const u16* __restrict__ Bt, int ldb,
    int m0, int n0, int K, float alpha, Epi epi)
{
    __shared__ u16 la[128 * 32];
    __shared__ u16 lb[128 * 32];

    const int tid  = threadIdx.x;
    const int lane = tid & 63;
    const int wave = tid >> 6;
    const int wm = (wave & 1) * 64;
    const int wn = (wave >> 1) * 64;

    f32x4 acc[4][4];
#pragma unroll
    for (int mt = 0; mt < 4; mt++)
#pragma unroll
        for (int nt = 0; nt < 4; nt++)
            acc[mt][nt] = f32x4{0.f, 0.f, 0.f, 0.f};

    const int mrow = wm + (lane & 15);
    const int nrow = wn + (lane & 15);
    const int koff = (lane >> 4) * 8;

    const int cb0 = wave * 64;
    const int cb1 = wave * 64 + 256;
    const int lrow = lane >> 2;
    const int lcol = (lane & 3) * 8;
    const u16* pa0 = A  + (size_t)(m0 + (cb0 >> 2) + lrow) * lda + lcol;
    const u16* pa1 = A  + (size_t)(m0 + (cb1 >> 2) + lrow) * lda + lcol;
    const u16* pb0 = Bt + (size_t)(n0 + (cb0 >> 2) + lrow) * ldb + lcol;
    const u16* pb1 = Bt + (size_t)(n0 + (cb1 >> 2) + lrow) * ldb + lcol;
    u16* qa0 = la + cb0 * 8;
    u16* qa1 = la + cb1 * 8;
    u16* qb0 = lb + cb0 * 8;
    u16* qb1 = lb + cb1 * 8;

    for (int kk = 0; kk < K; kk += 32) {
        __syncthreads();
        gload_lds16(pa0 + kk, qa0);
        gload_lds16(pa1 + kk, qa1);
        gload_lds16(pb0 + kk, qb0);
        gload_lds16(pb1 + kk, qb1);
        __syncthreads();

        bf16x8 fa[4], fb[4];
#pragma unroll
        for (int t = 0; t < 4; t++) {
            fa[t] = *(const bf16x8*)(la + (mrow + t * 16) * 32 + koff);
            fb[t] = *(const bf16x8*)(lb + (nrow + t * 16) * 32 + koff);
        }
#pragma unroll
        for (int mt = 0; mt < 4; mt++)
#pragma unroll
            for (int nt = 0; nt < 4; nt++)
                acc[mt][nt] = __builtin_amdgcn_mfma_f32_16x16x32_bf16(
                    fa[mt], fb[nt], acc[mt][nt], 0, 0, 0);
    }

    // C/D layout col=lane&15, row=(lane>>4)*4+reg  [verified m89/m91]
    const int col   = lane & 15;
    const int rquad = (lane >> 4) * 4;
#pragma unroll
    for (int mt = 0; mt < 4; mt++)
#pragma unroll
        for (int nt = 0; nt < 4; nt++) {
            const int n = n0 + wn + nt * 16 + col;
#pragma unroll
            for (int r = 0; r < 4; r++) {
                const int m = m0 + wm + mt * 16 + rquad + r;
                epi(m, n, acc[mt][nt][r] * alpha);
            }
        }
}

// ---------------- QKV projection ----------------
// which 0/1 -> q/k row-major; which 2 -> vT[b][f][s] written transposed.
// XCD swizzle: xcd = bx&7 owns m-tiles [16*xcd,16*xcd+16) -> A fetched once per XCD.
__global__ __launch_bounds__(256) void k_qkv(const u16* __restrict__ xb,
                                             const u16* __restrict__ Wb,
                                             const float* __restrict__ bq,
                                             const float* __restrict__ bk,
                                             const float* __restrict__ bv,
                                             u16* __restrict__ q,
                                             u16* __restrict__ k,
                                             u16* __restrict__ vT) {
    const int which = blockIdx.y;
    const int bx = blockIdx.x;
    const int xcd = bx & 7;
    const int idx = bx >> 3;
    const int m0 = (xcd * 16 + (idx >> 3)) * 128;
    const int n0 = (idx & 7) * 128;
    const float* bias = (which == 0) ? bq : (which == 1) ? bk : bv;
    const u16* W = Wb + (size_t)which * F_DIM * F_DIM;
    if (which < 2) {
        u16* o = (which == 0) ? q : k;
        gemm_tile_128(xb, F_DIM, W, F_DIM, m0, n0, F_DIM, 1.0f,
            [&](int m, int n, float v) {
                o[(size_t)m * F_DIM + n] = f32_to_bf16_rne(v + bias[n]);
            });
    } else {
        gemm_tile_128(xb, F_DIM, W, F_DIM, m0, n0, F_DIM, 1.0f,
            [&](int m, int n, float v) {
                // vT[b][n][s], b = m>>11, s = m&2047
                vT[((size_t)(m >> 11) * F_DIM + n) * S_LEN + (m & 2047)] =
                    f32_to_bf16_rne(v + bias[n]);
            });
    }
}

// ---------------- scores -> P' = exp(s-16) masked, bf16 + fused row sums ----------
// 1D grid 1088; batch = bx&7 -> XCD = batch. Each thread accumulates its 16
// (mt,r) partial row sums of the bf16 P' values it writes; after the GEMM a
// 16-lane shfl_xor col-reduce + one atomicAdd per row fragment accumulates
// into lsum[b][m] (zeroed by hipMemsetAsync before launch).
__global__ __launch_bounds__(256) void k_scores(const u16* __restrict__ q,
                                                const u16* __restrict__ k,
                                                const int* __restrict__ pad,
                                                u16* __restrict__ Pp,
                                                float* __restrict__ lsum) {
    const int b = blockIdx.x & 7;
    const int t = blockIdx.x >> 3;        // 0..135 triangular index
    int it = 0, base = 0;
    while (base + it + 1 <= t) { base += it + 1; it++; }
    const int jt = t - base;
    const int* padb = pad + b * S_LEN;
    u16* Pb = Pp + (size_t)b * S_LEN * S_LEN;

    float rs[16];
#pragma unroll
    for (int i = 0; i < 16; i++) rs[i] = 0.f;

    gemm_tile_128(q + (size_t)b * S_LEN * F_DIM, F_DIM,
                  k + (size_t)b * S_LEN * F_DIM, F_DIM,
                  it * 128, jt * 128, F_DIM, 0.03125f,
        [&](int m, int n, float v) {
            u16 o = 0;
            if (n <= m && padb[n] != 0)
                o = f32_to_bf16_rne(__expf(v - 16.0f));
            Pb[(size_t)m * S_LEN + n] = o;
            // i = wm-relative row id: mt*16 + rquad + r  (< 64)
            const int i = m & 63;
            rs[((i >> 4) << 2) | (i & 3)] += bf16_to_f32(o);
        });

    const int lane  = threadIdx.x & 63;
    const int wave  = threadIdx.x >> 6;
    const int wm    = (wave & 1) * 64;
    const int rquad = (lane >> 4) * 4;
    float* lb = lsum + b * S_LEN + it * 128 + wm;
#pragma unroll
    for (int i = 0; i < 16; i++) {        // i = mt*4 + r
        float s = rs[i];
        s += __shfl_xor(s, 1);
        s += __shfl_xor(s, 2);
        s += __shfl_xor(s, 4);
        s += __shfl_xor(s, 8);            // now uniform across the 16 col-lanes
        if ((lane & 15) == 0)
            atomicAdd(&lb[((i >> 2) << 4) + rquad + (i & 3)], s);
    }
}

// ---------------- PV: out = (P' @ V) / l, k-tiles clipped at diagonal ---------
// 1D grid 1024; batch = bx&7 -> XCD = batch. Heavy/light interleave on it:
// block work ~ Keff=(it+1)*128 (16:1 spread); ascending order clusters heavy
// blocks on CUs. j&1 ? j>>1 : 15-j>>1 gives 15,0,14,1,... so consecutively
// dispatched blocks pair heavy with light on each CU.
__global__ __launch_bounds__(256) void k_pv(const u16* __restrict__ Pp,
                                            const u16* __restrict__ vT,
                                            const float* __restrict__ lsum,
                                            float* __restrict__ out) {
    const int b = blockIdx.x & 7;
    const int rest = blockIdx.x >> 3;
    const int j = rest >> 3;
    const int nt = rest & 7;
    const int it = (j & 1) ? (j >> 1) : (15 - (j >> 1));
    const int Keff = (it + 1) * 128;
    const float* ls = lsum + b * S_LEN;
    float* ob = out + (size_t)b * S_LEN * F_DIM;

    // per-thread inverses for the 16 rows this thread writes (l final: k_scores done)
    const int lane  = threadIdx.x & 63;
    const int wave  = threadIdx.x >> 6;
    const int wm    = (wave & 1) * 64;
    const int rquad = (lane >> 4) * 4;
    const int mb    = it * 128 + wm;
    float myinv[16];
#pragma unroll
    for (int i = 0; i < 16; i++)          // i = mt*4 + r
        myinv[i] = 1.0f / ls[mb + ((i >> 2) << 4) + rquad + (i & 3)];

    gemm_tile_128(Pp + (size_t)b * S_LEN * S_LEN, S_LEN,
                  vT + (size_t)b * F_DIM * S_LEN, S_LEN,
                  it * 128, nt * 128, Keff, 1.0f,
        [&](int m, int n, float v) {
            const int i = m & 63;
            ob[(size_t)m * F_DIM + n] = v * myinv[((i >> 4) << 2) | (i & 3)];
        });
}

extern "C" void kernel_launch(void* const* d_in, const int* in_sizes, int n_in,
                              void* d_out, int out_size, void* d_ws, size_t ws_size,
                              hipStream_t stream) {
    const float* x  = (const float*)d_in[0];
    // d_in[1] = attn_mask (causal tril) — structure hard-coded
    const int* pad  = (const int*)d_in[2];
    const float* Wq = (const float*)d_in[3];
    const float* bq = (const float*)d_in[4];
    const float* Wk = (const float*)d_in[5];
    const float* bk = (const float*)d_in[6];
    const float* Wv = (const float*)d_in[7];
    const float* bv = (const float*)d_in[8];
    float* out = (float*)d_out;

    char* ws = (char*)d_ws;
    // layout:
    //   [0,32M)    q    bf16 [8][2048][1024]
    //   [32,64M)   k    bf16 [8][2048][1024]
    //   [64,96M)   vT   bf16 [8][1024][2048]
    //   [96,160M)  P'   bf16 [8][2048][2048]  (= masked exp(s-16); triangular written)
    //   [160,192M) xb   bf16 [16384][1024]
    //   [192,198M) Wb   bf16 [3][1024][1024]
    //   [200,200M+64K) lsum f32 [16384]  (row sums, atomic-accumulated)
    u16* q    = (u16*)(ws);
    u16* k    = (u16*)(ws + 32ull * 1024 * 1024);
    u16* vT   = (u16*)(ws + 64ull * 1024 * 1024);
    u16* Pp   = (u16*)(ws + 96ull * 1024 * 1024);
    u16* xb   = (u16*)(ws + 160ull * 1024 * 1024);
    u16* Wb   = (u16*)(ws + 192ull * 1024 * 1024);
    float* il = (float*)(ws + 200ull * 1024 * 1024);

    const int BSF = BS_TOT * F_DIM;      // 16,777,216
    const int FF = F_DIM * F_DIM;        // 1,048,576

    hipMemsetAsync(il, 0, BS_TOT * sizeof(float), stream);

    cvt_f32_bf16<<<BSF / 1024, 256, 0, stream>>>(x, xb, BSF);
    cvt_w3<<<dim3(FF / 1024, 3), 256, 0, stream>>>(Wq, Wk, Wv, Wb);

    k_qkv<<<dim3(1024, 3), 256, 0, stream>>>(xb, Wb, bq, bk, bv, q, k, vT);

    k_scores<<<1088, 256, 0, stream>>>(q, k, pad, Pp, il);

    k_pv<<<1024, 256, 0, stream>>>(Pp, vT, il, out);
}